// Round 15
// baseline (95.179 us; speedup 1.0000x reference)
//
#include <hip/hip_runtime.h>
#include <stdint.h>

#define B_ROWS 16384
#define C_CLS  2000
#define C_PAD  2048
#define F_DIM  1024
#define KT     16                         // K-tiles of 64
#define NRB    64                         // gemm row blocks (256 rows)
#define NCBP   16                         // gemm col panels (128 cols)
#define PANEL_A 262144                    // 16 kt x 8 frags x 2048 B
#define PANEL_BB 131072                   // 16 kt x 4 frags x 2048 B

typedef float f32x16 __attribute__((ext_vector_type(16)));
typedef int   i32x4  __attribute__((ext_vector_type(4)));
typedef int   i32x8  __attribute__((ext_vector_type(8)));

#define SCALE_F 4.0f
#define SCALE_W 16.0f
#define INV_SCALE 0.015625f               // 1/64
#define SCL1 0x7F7F7F7F                   // E8M0 = 127 -> 2^0 = 1.0 per block

__device__ __forceinline__ unsigned int pk4(float a, float b, float c, float d) {
    int u = __builtin_amdgcn_cvt_pk_fp8_f32(a, b, 0, false);   // bytes 0,1
    u = __builtin_amdgcn_cvt_pk_fp8_f32(c, d, u, true);        // bytes 2,3
    return (unsigned int)u;
}

// f8f6f4 32x32x64 fragment: frag covers 32 rows x 64 k; lane l holds row (l&31),
// k = (l>>5)*32 .. +32 (32 contiguous fp8 = one MX scale block); stored at
// frag_base + lane*32. Extends the verified non-scaled family layout.

// ---- fused prepass: blocks 0..511 = A (feat->fp8 + fisher), 512..639 = B (W->fp8 + bias) ----
__global__ __launch_bounds__(256)
void prep_kernel(const float* __restrict__ feat, const int* __restrict__ labels,
                 const float* __restrict__ centers, const float* __restrict__ W,
                 const float* __restrict__ bias,
                 char* __restrict__ A_pre, char* __restrict__ B_pre,
                 float* __restrict__ bias_pad, float* __restrict__ fisher_part)
{
    const int tid = threadIdx.x;
    if (blockIdx.x < 512) {
        const int rt = blockIdx.x >> 2, g = blockIdx.x & 3;   // rt: 128-row half-panels
        const int rb = rt >> 1;
        const int r = tid >> 1, h = tid & 1;
        const int grow = rt * 128 + r;
        const int lab = labels[grow];
        const float* frow = feat    + (size_t)grow * F_DIM;
        const float* crow = centers + (size_t)lab  * F_DIM;
        const int f = (rt & 1) * 4 + (r >> 5);                 // frag 0..7 in panel
        const int lane = (h << 5) | (r & 31);
        char* pbase = A_pre + (size_t)rb * PANEL_A + f * 2048 + lane * 32;
        float facc = 0.f;
        #pragma unroll
        for (int q = 0; q < 4; ++q) {
            const int kt = g * 4 + q;
            const int k0 = kt * 64 + h * 32;
            unsigned int o[8];
            #pragma unroll
            for (int c = 0; c < 8; ++c) {
                float4 av = *(const float4*)(frow + k0 + c * 4);
                float4 cv = *(const float4*)(crow + k0 + c * 4);
                float d0 = av.x - cv.x, d1 = av.y - cv.y, d2 = av.z - cv.z, d3 = av.w - cv.w;
                facc += d0 * d0 + d1 * d1 + d2 * d2 + d3 * d3;
                o[c] = pk4(SCALE_F * av.x, SCALE_F * av.y, SCALE_F * av.z, SCALE_F * av.w);
            }
            char* dst = pbase + kt * 16384;
            *(uint4*)(dst)      = (uint4){o[0], o[1], o[2], o[3]};
            *(uint4*)(dst + 16) = (uint4){o[4], o[5], o[6], o[7]};
        }
        for (int d = 32; d >= 1; d >>= 1) facc += __shfl_xor(facc, d);
        __shared__ float redw[4];
        const int wid = tid >> 6, ln = tid & 63;
        if (ln == 0) redw[wid] = facc;
        __syncthreads();
        if (tid == 0) fisher_part[blockIdx.x] = redw[0] + redw[1] + redw[2] + redw[3];
    } else {
        const int b = blockIdx.x - 512;
        const int ct = b >> 3, ktg = b & 7;
        const int cb = ct >> 1;
        const int rcol = tid >> 1, h = tid & 1;
        const int gc = ct * 128 + rcol;
        const int f = (ct & 1) * 2 + (rcol >> 5);              // frag 0..3 in panel
        const int lane = (h << 5) | (rcol & 31);
        char* pbase = B_pre + (size_t)cb * PANEL_BB + f * 2048 + lane * 32;
        #pragma unroll
        for (int q = 0; q < 2; ++q) {
            const int kt = ktg * 2 + q;
            const int k0 = kt * 64 + h * 32;
            unsigned int o[8];
            if (gc < C_CLS) {
                const float* src = W + (size_t)gc * F_DIM + k0;
                #pragma unroll
                for (int c = 0; c < 8; ++c) {
                    float4 av = *(const float4*)(src + c * 4);
                    o[c] = pk4(SCALE_W * av.x, SCALE_W * av.y, SCALE_W * av.z, SCALE_W * av.w);
                }
            } else {
                #pragma unroll
                for (int c = 0; c < 8; ++c) o[c] = 0u;
            }
            char* dst = pbase + kt * 8192;
            *(uint4*)(dst)      = (uint4){o[0], o[1], o[2], o[3]};
            *(uint4*)(dst + 16) = (uint4){o[4], o[5], o[6], o[7]};
        }
        if (b < C_PAD / 256) {
            const int i = b * 256 + tid;
            bias_pad[i] = (i < C_CLS) ? bias[i] : -1e30f;
        }
    }
}

// ---- 256x128 MX-fp8 flat-MFMA GEMM (32x32x64 scaled, scales=1.0), global->reg ----
__global__ __launch_bounds__(256, 2)
void gemm_kernel(const int* __restrict__ labels, const float* __restrict__ biasp,
                 const char* __restrict__ A_pre, const char* __restrict__ B_pre,
                 float* __restrict__ s_part, float* __restrict__ tl_part)
{
    const int cpx = gridDim.x >> 3;                 // XCD swizzle: same-XCD blocks share rb
    const int wg = (blockIdx.x & 7) * cpx + (blockIdx.x >> 3);
    const int cb = wg & 15;
    const int rb = wg >> 4;

    const int tid = threadIdx.x;
    const int w = tid >> 6, lane = tid & 63;
    const int l31 = lane & 31, lh = lane >> 5;

    const char* Apan = A_pre + (size_t)rb * PANEL_A + w * 4096 + lane * 32;  // frags w*2, w*2+1
    const char* Bpan = B_pre + (size_t)cb * PANEL_BB + lane * 32;

    f32x16 acc[2][4];
    #pragma unroll
    for (int mi = 0; mi < 2; ++mi)
        #pragma unroll
        for (int ni = 0; ni < 4; ++ni)
            #pragma unroll
            for (int e = 0; e < 16; ++e) acc[mi][ni][e] = 0.f;

    i32x8 aE[2], bE[4], aO[2], bO[4];

#define LOAD32B(DST, P) do {                                                          \
    *(i32x4*)&(DST)       = *(const i32x4*)(P);                                       \
    *(((i32x4*)&(DST))+1) = *(const i32x4*)((P) + 16);                                \
} while (0)

#define LOADT(SA, SB, KTT) do {                                                       \
    const char* pa_ = Apan + (KTT) * 16384;                                           \
    const char* pb_ = Bpan + (KTT) * 8192;                                            \
    _Pragma("unroll")                                                                 \
    for (int i_ = 0; i_ < 2; ++i_) LOAD32B(SA[i_], pa_ + i_ * 2048);                  \
    _Pragma("unroll")                                                                 \
    for (int i_ = 0; i_ < 4; ++i_) LOAD32B(SB[i_], pb_ + i_ * 2048);                  \
} while (0)

#define MFMA8(SA, SB) do {                                                            \
    __builtin_amdgcn_s_setprio(1);                                                    \
    _Pragma("unroll")                                                                 \
    for (int mi_ = 0; mi_ < 2; ++mi_)                                                 \
        _Pragma("unroll")                                                             \
        for (int ni_ = 0; ni_ < 4; ++ni_)                                             \
            acc[mi_][ni_] = __builtin_amdgcn_mfma_scale_f32_32x32x64_f8f6f4(          \
                SA[mi_], SB[ni_], acc[mi_][ni_], 0, 0, 0, SCL1, 0, SCL1);             \
    __builtin_amdgcn_s_setprio(0);                                                    \
} while (0)

#define FENCE __builtin_amdgcn_sched_barrier(0)

    LOADT(aE, bE, 0);
    FENCE;
    #pragma unroll 1
    for (int k2 = 0; k2 < 7; ++k2) {
        LOADT(aO, bO, 2 * k2 + 1);      // issue next-tile loads first (latency cover)
        FENCE;
        MFMA8(aE, bE);                   // compiler inserts counted vmcnt before O-use
        FENCE;
        LOADT(aE, bE, 2 * k2 + 2);
        FENCE;
        MFMA8(aO, bO);
        FENCE;
    }
    LOADT(aO, bO, 15);
    FENCE;
    MFMA8(aE, bE);                       // tile 14
    MFMA8(aO, bO);                       // tile 15

#undef LOADT
#undef LOAD32B
#undef MFMA8
#undef FENCE

    // epilogue: 32x32 C/D layout (col = lane&31, row = (reg&3)+8*(reg>>2)+4*(lane>>5))
    float bb[4];
    #pragma unroll
    for (int ni = 0; ni < 4; ++ni)
        bb[ni] = biasp[cb * 128 + ni * 32 + l31];

    #pragma unroll
    for (int mi = 0; mi < 2; ++mi) {
        #pragma unroll
        for (int reg = 0; reg < 16; ++reg) {
            const int rl = w * 64 + mi * 32 + (reg & 3) + 8 * (reg >> 2) + 4 * lh;
            const int lab = labels[rb * 256 + rl];
            float sv = 0.f, tv = 0.f;
            #pragma unroll
            for (int ni = 0; ni < 4; ++ni) {
                const float v = fmaf(acc[mi][ni][reg], INV_SCALE, bb[ni]);
                sv += __expf(v);
                const int gc = cb * 128 + ni * 32 + l31;
                tv = (gc == lab) ? v : tv;
            }
            #pragma unroll
            for (int d = 1; d < 32; d <<= 1) {
                sv += __shfl_xor(sv, d);
                tv += __shfl_xor(tv, d);
            }
            if (l31 == 0) {
                const int grow = rb * 256 + rl;
                s_part[(size_t)cb * B_ROWS + grow]  = sv;
                tl_part[(size_t)cb * B_ROWS + grow] = tv;
            }
        }
    }
}

// ---- combine partials across the 16 column panels, per-row aux loss ----
__global__ __launch_bounds__(256)
void rowcomb_kernel(const float* __restrict__ s_part, const float* __restrict__ tl_part,
                    float* __restrict__ aux_part)
{
    const int row = blockIdx.x * 256 + threadIdx.x;
    float s = 0.f, t = 0.f;
    #pragma unroll
    for (int p = 0; p < NCBP; ++p) {
        s += s_part[(size_t)p * B_ROWS + row];
        t += tl_part[(size_t)p * B_ROWS + row];
    }
    float acc = __logf(s) - t;
    for (int d = 32; d >= 1; d >>= 1) acc += __shfl_xor(acc, d);
    __shared__ float red[4];
    const int wid = threadIdx.x >> 6, lane = threadIdx.x & 63;
    if (lane == 0) red[wid] = acc;
    __syncthreads();
    if (threadIdx.x == 0) aux_part[blockIdx.x] = red[0] + red[1] + red[2] + red[3];
}

__global__ __launch_bounds__(256)
void final_kernel(const float* __restrict__ fisher_part, const float* __restrict__ aux_part,
                  float* __restrict__ out)
{
    const int tid = threadIdx.x;
    float acc = fisher_part[tid] + fisher_part[256 + tid];
    if (tid < 64) acc += aux_part[tid];
    for (int d = 32; d >= 1; d >>= 1) acc += __shfl_xor(acc, d);
    __shared__ float red[4];
    const int wid = tid >> 6, lane = tid & 63;
    if (lane == 0) red[wid] = acc;
    __syncthreads();
    if (tid == 0) out[0] = (red[0] + red[1] + red[2] + red[3]) * (1.0f / (float)B_ROWS);
}

extern "C" void kernel_launch(void* const* d_in, const int* in_sizes, int n_in,
                              void* d_out, int out_size, void* d_ws, size_t ws_size,
                              hipStream_t stream)
{
    (void)in_sizes; (void)n_in; (void)out_size; (void)ws_size;
    const float* feat    = (const float*)d_in[0];
    const int*   labels  = (const int*)  d_in[1];
    const float* centers = (const float*)d_in[2];
    const float* W       = (const float*)d_in[3];
    const float* bias    = (const float*)d_in[4];
    float* out = (float*)d_out;
    char* ws = (char*)d_ws;

    const size_t szA    = (size_t)NRB  * PANEL_A;   // 16,777,216
    const size_t szB    = (size_t)NCBP * PANEL_BB;  //  2,097,152
    const size_t szBias = (size_t)C_PAD * 4;

    char* A_pre = ws;
    char* B_pre = ws + szA;
    float* bias_pad    = (float*)(ws + szA + szB);
    float* s_part      = (float*)(ws + szA + szB + szBias);
    float* tl_part     = s_part + (size_t)NCBP * B_ROWS;
    float* fisher_part = tl_part + (size_t)NCBP * B_ROWS;
    float* aux_part    = fisher_part + 512;

    prep_kernel<<<640, 256, 0, stream>>>(feat, labels, centers, W, bias,
                                         A_pre, B_pre, bias_pad, fisher_part);
    gemm_kernel<<<NRB * NCBP, 256, 0, stream>>>(labels, bias_pad, A_pre, B_pre, s_part, tl_part);
    rowcomb_kernel<<<B_ROWS / 256, 256, 0, stream>>>(s_part, tl_part, aux_part);
    final_kernel<<<1, 256, 0, stream>>>(fisher_part, aux_part, out);
}